// Round 1
// baseline (84.272 us; speedup 1.0000x reference)
//
#include <hip/hip_runtime.h>

// K = 2097152 rows. out[k] = M[k] (4x4) @ T[k] where
// T = [[R, p],[0,0,0,1]],
// R = I + sin(th)*S(u) + (1-cos(th))*(S(u) elemwise-sq), th = ||w_k|| per-row
// p = V @ rho, V = I + b*S(w) + c*(S(w) elemwise-sq),
// b,c from GLOBAL Frobenius norm of all of tau[:,3:] (reference quirk).

#define NPART 2048

__global__ __launch_bounds__(256) void reduce_ss(const float4* __restrict__ tau4,
                                                 int n4,
                                                 double* __restrict__ partial) {
    int tid = blockIdx.x * blockDim.x + threadIdx.x;
    int stride = gridDim.x * blockDim.x;
    float acc = 0.f;
    for (int i = tid; i < n4; i += stride) {
        float4 v = tau4[i];
        int r = (4 * i) % 6;  // 0, 2, or 4 (4i is even)
        if (r == 0) {
            acc += v.w * v.w;                          // flat idx 3
        } else if (r == 2) {
            acc += v.y * v.y + v.z * v.z + v.w * v.w;  // flat idx 3,4,5
        } else {
            acc += v.x * v.x + v.y * v.y;              // flat idx 4,5
        }
    }
    double d = (double)acc;
    #pragma unroll
    for (int off = 32; off > 0; off >>= 1)
        d += __shfl_down(d, off, 64);
    __shared__ double sdata[4];
    int lane = threadIdx.x & 63;
    int wid = threadIdx.x >> 6;
    if (lane == 0) sdata[wid] = d;
    __syncthreads();
    if (threadIdx.x == 0)
        partial[blockIdx.x] = sdata[0] + sdata[1] + sdata[2] + sdata[3];
}

__global__ __launch_bounds__(256) void finalize_bc(const double* __restrict__ partial,
                                                   int n,
                                                   float* __restrict__ bc) {
    double d = 0.0;
    for (int i = threadIdx.x; i < n; i += blockDim.x) d += partial[i];
    #pragma unroll
    for (int off = 32; off > 0; off >>= 1)
        d += __shfl_down(d, off, 64);
    __shared__ double sdata[4];
    int lane = threadIdx.x & 63;
    int wid = threadIdx.x >> 6;
    if (lane == 0) sdata[wid] = d;
    __syncthreads();
    if (threadIdx.x == 0) {
        double ss = sdata[0] + sdata[1] + sdata[2] + sdata[3];
        double th = sqrt(ss);
        double b = (1.0 - cos(th)) / ss;         // (1-cos)/th^2
        double c = (th - sin(th)) / (ss * th);   // (th-sin)/th^3
        bc[0] = (float)b;
        bc[1] = (float)c;
    }
}

__global__ __launch_bounds__(256) void se3_apply(const float4* __restrict__ M4,
                                                 const float2* __restrict__ tau2,
                                                 const float* __restrict__ bc,
                                                 float4* __restrict__ out4,
                                                 int k) {
    int i = blockIdx.x * blockDim.x + threadIdx.x;
    if (i >= k) return;
    float b = bc[0], c = bc[1];

    float2 t0 = tau2[(size_t)i * 3 + 0];
    float2 t1 = tau2[(size_t)i * 3 + 1];
    float2 t2 = tau2[(size_t)i * 3 + 2];
    float rx = t0.x, ry = t0.y, rz = t1.x;
    float wx = t1.y, wy = t2.x, wz = t2.y;

    float th = sqrtf(wx * wx + wy * wy + wz * wz);
    float s, ct;
    sincosf(th, &s, &ct);
    float omc = 1.f - ct;
    float inv = 1.f / th;
    float ux = wx * inv, uy = wy * inv, uz = wz * inv;

    // R (diag exactly 1 — reference uses elementwise S*S)
    float R01 = -s * uz + omc * uz * uz;
    float R02 =  s * uy + omc * uy * uy;
    float R10 =  s * uz + omc * uz * uz;
    float R12 = -s * ux + omc * ux * ux;
    float R20 = -s * uy + omc * uy * uy;
    float R21 =  s * ux + omc * ux * ux;

    // V with global scalars b,c (reference quirk: Frobenius norm over ALL rows)
    float V01 = -b * wz + c * wz * wz, V02 =  b * wy + c * wy * wy;
    float V10 =  b * wz + c * wz * wz, V12 = -b * wx + c * wx * wx;
    float V20 = -b * wy + c * wy * wy, V21 =  b * wx + c * wx * wx;
    float p0 = rx + V01 * ry + V02 * rz;
    float p1 = V10 * rx + ry + V12 * rz;
    float p2 = V20 * rx + V21 * ry + rz;

    const float4* Mi = M4 + (size_t)i * 4;
    float4* Oi = out4 + (size_t)i * 4;
    #pragma unroll
    for (int r = 0; r < 4; ++r) {
        float4 m = Mi[r];
        float4 o;
        o.x = m.x        + m.y * R10 + m.z * R20;
        o.y = m.x * R01  + m.y       + m.z * R21;
        o.z = m.x * R02  + m.y * R12 + m.z;
        o.w = m.x * p0   + m.y * p1  + m.z * p2 + m.w;
        Oi[r] = o;
    }
}

extern "C" void kernel_launch(void* const* d_in, const int* in_sizes, int n_in,
                              void* d_out, int out_size, void* d_ws, size_t ws_size,
                              hipStream_t stream) {
    const float* M = (const float*)d_in[0];
    const float* tau = (const float*)d_in[1];
    int k = in_sizes[1] / 6;

    double* partial = (double*)d_ws;
    float* bc = (float*)((char*)d_ws + NPART * sizeof(double));

    int n4 = (k * 6) / 4;  // tau flat floats / 4
    reduce_ss<<<NPART, 256, 0, stream>>>((const float4*)tau, n4, partial);
    finalize_bc<<<1, 256, 0, stream>>>(partial, NPART, bc);

    int grid = (k + 255) / 256;
    se3_apply<<<grid, 256, 0, stream>>>((const float4*)M, (const float2*)tau, bc,
                                        (float4*)d_out, k);
}

// Round 2
// 69.192 us; speedup vs baseline: 1.2179x; 1.2179x over previous
//
#include <hip/hip_runtime.h>

// K = 2097152 rows. out[k] = M[k] (4x4) @ T[k] where
// T = [[R, p],[0,0,0,1]],
// R = I + sin(th)*S(u) + (1-cos(th))*(S(u) elemwise-sq), th = ||w_k|| per-row
// p = V @ rho, V = I + b*S(w) + c*(S(w) elemwise-sq),
// b,c from GLOBAL Frobenius norm of all of tau[:,3:] (reference quirk).
//
// se3_apply: 4 threads per row (thread j -> row j>>2, matrix-row j&3) so that
// M loads and out stores are perfectly coalesced 16B/lane streams. The scalar
// row math (sincos, R, p) is recomputed by each 4-lane group: VALU was 9%
// busy in the 1-thread/row version, so 4x redundancy is free; the win is
// killing the 64B-stride lane scatter that capped BW at ~2.9 TB/s.

#define NPART 2048

__global__ __launch_bounds__(256) void reduce_ss(const float4* __restrict__ tau4,
                                                 int n4,
                                                 double* __restrict__ partial) {
    int tid = blockIdx.x * blockDim.x + threadIdx.x;
    int stride = gridDim.x * blockDim.x;
    float acc = 0.f;
    for (int i = tid; i < n4; i += stride) {
        float4 v = tau4[i];
        int r = (4 * i) % 6;  // 0, 2, or 4 (4i is even)
        if (r == 0) {
            acc += v.w * v.w;                          // flat idx 3
        } else if (r == 2) {
            acc += v.y * v.y + v.z * v.z + v.w * v.w;  // flat idx 3,4,5
        } else {
            acc += v.x * v.x + v.y * v.y;              // flat idx 4,5
        }
    }
    double d = (double)acc;
    #pragma unroll
    for (int off = 32; off > 0; off >>= 1)
        d += __shfl_down(d, off, 64);
    __shared__ double sdata[4];
    int lane = threadIdx.x & 63;
    int wid = threadIdx.x >> 6;
    if (lane == 0) sdata[wid] = d;
    __syncthreads();
    if (threadIdx.x == 0)
        partial[blockIdx.x] = sdata[0] + sdata[1] + sdata[2] + sdata[3];
}

__global__ __launch_bounds__(256) void finalize_bc(const double* __restrict__ partial,
                                                   int n,
                                                   float* __restrict__ bc) {
    double d = 0.0;
    for (int i = threadIdx.x; i < n; i += blockDim.x) d += partial[i];
    #pragma unroll
    for (int off = 32; off > 0; off >>= 1)
        d += __shfl_down(d, off, 64);
    __shared__ double sdata[4];
    int lane = threadIdx.x & 63;
    int wid = threadIdx.x >> 6;
    if (lane == 0) sdata[wid] = d;
    __syncthreads();
    if (threadIdx.x == 0) {
        double ss = sdata[0] + sdata[1] + sdata[2] + sdata[3];
        double th = sqrt(ss);
        double b = (1.0 - cos(th)) / ss;         // (1-cos)/th^2
        double c = (th - sin(th)) / (ss * th);   // (th-sin)/th^3
        bc[0] = (float)b;
        bc[1] = (float)c;
    }
}

__global__ __launch_bounds__(256) void se3_apply(const float4* __restrict__ M4,
                                                 const float2* __restrict__ tau2,
                                                 const float* __restrict__ bc,
                                                 float4* __restrict__ out4,
                                                 int k4) {
    int j = blockIdx.x * blockDim.x + threadIdx.x;  // one float4 row of M/out
    if (j >= k4) return;
    int i = j >> 2;  // SE3 row index

    float b = bc[0], c = bc[1];

    // tau row i (4 lanes in a group read the same addresses -> L1 broadcast)
    float2 t0 = tau2[(size_t)i * 3 + 0];
    float2 t1 = tau2[(size_t)i * 3 + 1];
    float2 t2 = tau2[(size_t)i * 3 + 2];
    float rx = t0.x, ry = t0.y, rz = t1.x;
    float wx = t1.y, wy = t2.x, wz = t2.y;

    float ss = wx * wx + wy * wy + wz * wz;
    float invr = rsqrtf(ss);
    float th = ss * invr;
    float s, ct;
    __sincosf(th, &s, &ct);
    float omc = 1.f - ct;
    float ux = wx * invr, uy = wy * invr, uz = wz * invr;

    // R (diag exactly 1 — reference uses elementwise S*S)
    float R01 = -s * uz + omc * uz * uz;
    float R02 =  s * uy + omc * uy * uy;
    float R10 =  s * uz + omc * uz * uz;
    float R12 = -s * ux + omc * ux * ux;
    float R20 = -s * uy + omc * uy * uy;
    float R21 =  s * ux + omc * ux * ux;

    // V with global scalars b,c (reference quirk: Frobenius norm over ALL rows)
    float V01 = -b * wz + c * wz * wz, V02 =  b * wy + c * wy * wy;
    float V10 =  b * wz + c * wz * wz, V12 = -b * wx + c * wx * wx;
    float V20 = -b * wy + c * wy * wy, V21 =  b * wx + c * wx * wx;
    float p0 = rx + V01 * ry + V02 * rz;
    float p1 = V10 * rx + ry + V12 * rz;
    float p2 = V20 * rx + V21 * ry + rz;

    float4 m = M4[j];   // coalesced: lane l reads 16B at base + l*16
    float4 o;
    o.x = m.x       + m.y * R10 + m.z * R20;
    o.y = m.x * R01 + m.y       + m.z * R21;
    o.z = m.x * R02 + m.y * R12 + m.z;
    o.w = m.x * p0  + m.y * p1  + m.z * p2 + m.w;
    out4[j] = o;        // coalesced
}

extern "C" void kernel_launch(void* const* d_in, const int* in_sizes, int n_in,
                              void* d_out, int out_size, void* d_ws, size_t ws_size,
                              hipStream_t stream) {
    const float* M = (const float*)d_in[0];
    const float* tau = (const float*)d_in[1];
    int k = in_sizes[1] / 6;

    double* partial = (double*)d_ws;
    float* bc = (float*)((char*)d_ws + NPART * sizeof(double));

    int n4 = (k * 6) / 4;  // tau flat floats / 4
    reduce_ss<<<NPART, 256, 0, stream>>>((const float4*)tau, n4, partial);
    finalize_bc<<<1, 256, 0, stream>>>(partial, NPART, bc);

    int k4 = k * 4;
    int grid = (k4 + 255) / 256;
    se3_apply<<<grid, 256, 0, stream>>>((const float4*)M, (const float2*)tau, bc,
                                        (float4*)d_out, k4);
}